// Round 13
// baseline (254.658 us; speedup 1.0000x reference)
//
#include <hip/hip_runtime.h>

#define C 256
#define HW 4096
#define CHW (C*HW)            // 1048576 elements per batch per tensor (2^20)
#define CPG 8
#define GELEMS (CPG*HW)

typedef __attribute__((ext_vector_type(8))) short short8;     // 8 bf16 = 4 VGPRs
typedef __attribute__((ext_vector_type(4))) float floatx4;    // 16x16 C/D frag
typedef __attribute__((ext_vector_type(16))) float floatx16;  // 32x32 C/D frag

__device__ __forceinline__ unsigned short f2bf(float x) {
  union { float f; unsigned int u; } v; v.f = x;
  unsigned int r = v.u + 0x7FFF + ((v.u >> 16) & 1);   // RNE
  return (unsigned short)(r >> 16);
}
__device__ __forceinline__ float bf2f(unsigned short u) {
  union { float f; unsigned int v; } x; x.v = ((unsigned int)u) << 16; return x.f;
}

// ---------------- GroupNorm -> hT (b,s,c) bf16  +  weight cast ----------------
__global__ __launch_bounds__(256) void gn_kernel(const float* __restrict__ x,
    const float* __restrict__ gw, const float* __restrict__ gb,
    unsigned short* __restrict__ hT,
    const float* __restrict__ wq, const float* __restrict__ wk,
    const float* __restrict__ wv, const float* __restrict__ wp,
    unsigned short* __restrict__ wbuf) {
  int blk = blockIdx.x;
  int t = threadIdx.x;

  if (blk >= 256) {
    int r = blk - 256;
    int y = r >> 3, sub = r & 7;
    const float* src = (y == 0) ? wq : (y == 1) ? wk : (y == 2) ? wv : wp;
    int i = sub * 8192 + t * 4;
    float4 v = *(const float4*)(src + i);
    ushort4 u;
    u.x = f2bf(v.x); u.y = f2bf(v.y); u.z = f2bf(v.z); u.w = f2bf(v.w);
    *(ushort4*)(wbuf + y * 65536 + i) = u;
    return;
  }

  int gq = blk >> 1, halfg = blk & 1;   // group 0..127 (b*32+g), half 0/1
  int b = gq >> 5, g = gq & 31;
  const float* xg = x + (size_t)gq * GELEMS;
  const float4* x4 = (const float4*)xg;

  float s = 0.f, ss = 0.f;
  for (int i = t; i < GELEMS/4; i += 256) {
    float4 v = x4[i];
    s  += v.x + v.y + v.z + v.w;
    ss += v.x*v.x + v.y*v.y + v.z*v.z + v.w*v.w;
  }
  #pragma unroll
  for (int off = 32; off > 0; off >>= 1) {
    s  += __shfl_down(s,  off, 64);
    ss += __shfl_down(ss, off, 64);
  }
  __shared__ float rs[4], rss[4];
  __shared__ float smean, sinv;
  int wid = t >> 6;
  if ((t & 63) == 0) { rs[wid] = s; rss[wid] = ss; }
  __syncthreads();
  if (t == 0) {
    float S  = rs[0] + rs[1] + rs[2] + rs[3];
    float SS = rss[0] + rss[1] + rss[2] + rss[3];
    float mean = S / (float)GELEMS;
    float var  = SS / (float)GELEMS - mean * mean;
    smean = mean;
    sinv  = rsqrtf(var + 1e-5f);
  }
  __syncthreads();
  float mean = smean, inv = sinv;
  float sa[8], sb[8];
  #pragma unroll
  for (int cc = 0; cc < 8; ++cc) {
    sa[cc] = inv * gw[g*CPG + cc];
    sb[cc] = gb[g*CPG + cc] - mean * sa[cc];
  }
  int sbeg = halfg * 2048;
  #pragma unroll
  for (int p = 0; p < 8; ++p) {
    int sl = sbeg + p*256 + t;
    short8 pk;
    #pragma unroll
    for (int cc = 0; cc < 8; ++cc)
      pk[cc] = (short)f2bf(xg[cc*HW + sl] * sa[cc] + sb[cc]);
    *(short8*)&hT[((size_t)b*HW + sl) * 256 + g*CPG] = pk;
  }
}

// ---------------- fused QKV GEMM with LDS-bounced coalesced stores ----------
// q,k: (s,c) layout, q pre-scaled by C^-0.5. v: packed B-frag tiles.
#define QT_PAD 272   // LDS row stride (shorts) for q/k bounce: conflict-free

__global__ __launch_bounds__(256) void qkv_kernel(const unsigned short* __restrict__ hT,
    const unsigned short* __restrict__ wqb, const float* __restrict__ bq,
    const unsigned short* __restrict__ wkb, const float* __restrict__ bk,
    const unsigned short* __restrict__ wvb, const float* __restrict__ bv,
    unsigned short* __restrict__ qo, unsigned short* __restrict__ ko,
    unsigned short* __restrict__ vo) {
  __shared__ __align__(16) unsigned short tile[64 * QT_PAD];   // 34.8 KB
  int stile = blockIdx.x, which = blockIdx.y, b = blockIdx.z;
  int t = threadIdx.x, w = t >> 6, lane = t & 63;
  int n16 = lane & 15, q8 = lane >> 4;
  int s0 = stile * 64;
  const unsigned short* hB = hT + (size_t)b * CHW;
  const unsigned short* W = (which == 0) ? wqb : (which == 1) ? wkb : wvb;
  const float* bias = (which == 0) ? bq : (which == 1) ? bk : bv;
  float scale = (which == 0) ? 0.0625f : 1.0f;

  floatx4 acc[4][4];
  #pragma unroll
  for (int i = 0; i < 4; ++i)
    #pragma unroll
    for (int j = 0; j < 4; ++j) acc[i][j] = (floatx4){0.f,0.f,0.f,0.f};

  for (int kt = 0; kt < 8; ++kt) {
    short8 af[4], bf[4];
    #pragma unroll
    for (int mt = 0; mt < 4; ++mt)
      af[mt] = *(const short8*)&hB[(size_t)(s0 + mt*16 + n16) * 256 + kt*32 + q8*8];
    #pragma unroll
    for (int nt = 0; nt < 4; ++nt)
      bf[nt] = *(const short8*)&W[(size_t)(w*64 + nt*16 + n16) * 256 + kt*32 + q8*8];
    #pragma unroll
    for (int mt = 0; mt < 4; ++mt)
      #pragma unroll
      for (int nt = 0; nt < 4; ++nt)
        acc[mt][nt] = __builtin_amdgcn_mfma_f32_16x16x32_bf16(af[mt], bf[nt], acc[mt][nt], 0, 0, 0);
  }
  float bias_v[4];
  #pragma unroll
  for (int nt = 0; nt < 4; ++nt) bias_v[nt] = bias[w*64 + nt*16 + n16];

  if (which < 2) {
    // ---- bounce (s,c) tile through LDS, then coalesced b128 stores ----
    #pragma unroll
    for (int mt = 0; mt < 4; ++mt)
      #pragma unroll
      for (int nt = 0; nt < 4; ++nt)
        #pragma unroll
        for (int r = 0; r < 4; ++r)
          tile[(mt*16 + q8*4 + r) * QT_PAD + w*64 + nt*16 + n16] =
              f2bf((acc[mt][nt][r] + bias_v[nt]) * scale);
    __syncthreads();
    unsigned short* oB = (which ? ko : qo) + (size_t)b * CHW + (size_t)s0 * 256;
    #pragma unroll
    for (int i = 0; i < 8; ++i) {
      int f = i*256 + t; int row = f >> 5, col8 = f & 31;
      *(short8*)(oB + row*256 + col8*8) = *(const short8*)&tile[row*QT_PAD + col8*8];
    }
  } else {
    // ---- bounce packed-V region (flat 32 KB) through LDS ----
    #pragma unroll
    for (int mt = 0; mt < 4; ++mt) {
      #pragma unroll
      for (int nt = 0; nt < 4; ++nt) {
        int c = w*64 + nt*16 + n16;
        int ct8 = c >> 5, c5 = c & 31;
        #pragma unroll
        for (int r = 0; r < 4; ++r) {
          int sl = q8*4 + r;                 // s within 16-row tile
          int hh = sl >> 3, e = sl & 7;
          tile[(mt*8 + ct8)*512 + (hh*32 + c5)*8 + e] =
              f2bf(acc[mt][nt][r] + bias_v[nt]);
        }
      }
    }
    __syncthreads();
    unsigned short* vB = vo + (size_t)b * CHW + (size_t)stile * 16384;
    #pragma unroll
    for (int i = 0; i < 8; ++i) {
      int f = i*256 + t;
      *(short8*)(vB + f*8) = *(const short8*)&tile[f*8];
    }
  }
}

// ---------------- MFMA flash attention (byte-identical to R10/R12) ----------
#define KS_PAD 264   // shorts per Ks row (256 + 8)
#define PS_PAD 72    // shorts per Ps row (64 + 8)

__global__ __launch_bounds__(256, 2) void att_kernel(
    const unsigned short* __restrict__ qb,
    const unsigned short* __restrict__ kb,
    const unsigned short* __restrict__ vb,
    unsigned short* __restrict__ P1, unsigned short* __restrict__ P2,
    float* __restrict__ l_arr) {
  __shared__ __align__(16) unsigned short Ks[64 * KS_PAD];
  __shared__ __align__(16) unsigned short Ps[64 * PS_PAD];
  __shared__ float Ls[2][64];
  __shared__ float Lc[64];

  int t = threadIdx.x, w = t >> 6, lane = t & 63;
  int m32 = lane & 31;
  int h   = lane >> 5;
  int qblk = w & 1;
  int mblk = w >> 1;
  int n0 = blockIdx.x * 64, half = blockIdx.y, b = blockIdx.z;

  const unsigned short* qB = qb + (size_t)b * CHW;
  const unsigned short* kB = kb + (size_t)b * CHW;
  const unsigned short* vB = vb + (size_t)b * CHW;

  short8 qf[16];
  {
    const unsigned short* qp = qB + (size_t)(n0 + qblk*32 + m32) * 256 + h*8;
    #pragma unroll
    for (int ks = 0; ks < 16; ++ks) qf[ks] = *(const short8*)(qp + ks*16);
  }

  float lsum[16];
  #pragma unroll
  for (int r = 0; r < 16; ++r) lsum[r] = 0.f;
  floatx16 oacc[2][2];
  #pragma unroll
  for (int i = 0; i < 2; ++i)
    #pragma unroll
    for (int j = 0; j < 2; ++j)
      #pragma unroll
      for (int r = 0; r < 16; ++r) oacc[i][j][r] = 0.f;

  int mc_beg = half * 32, mc_end = mc_beg + 32;
  short8 kreg[8];
  #pragma unroll
  for (int i = 0; i < 8; ++i) {
    int f = i*256 + t; int row = f >> 5, col8 = f & 31;
    kreg[i] = *(const short8*)(kB + (size_t)(mc_beg*64 + row) * 256 + col8*8);
  }

  for (int mc = mc_beg; mc < mc_end; ++mc) {
    int m0 = mc * 64;
    #pragma unroll
    for (int i = 0; i < 8; ++i) {
      int f = i*256 + t; int row = f >> 5, col8 = f & 31;
      *(short8*)&Ks[row * KS_PAD + col8*8] = kreg[i];
    }
    __syncthreads();
    if (mc + 1 < mc_end) {
      #pragma unroll
      for (int i = 0; i < 8; ++i) {
        int f = i*256 + t; int row = f >> 5, col8 = f & 31;
        kreg[i] = *(const short8*)(kB + (size_t)(m0 + 64 + row) * 256 + col8*8);
      }
    }
    short8 vreg[4][2];
    #pragma unroll
    for (int ks2 = 0; ks2 < 4; ++ks2)
      #pragma unroll
      for (int ct = 0; ct < 2; ++ct)
        vreg[ks2][ct] = *(const short8*)(vB +
            ((size_t)(mc*4 + ks2)*8 + (w*2 + ct))*512 + lane*8);

    floatx16 sa_, sb_;
    #pragma unroll
    for (int r = 0; r < 16; ++r) { sa_[r] = 0.f; sb_[r] = 0.f; }
    #pragma unroll
    for (int ks = 0; ks < 8; ++ks) {
      short8 bk0 = *(const short8*)&Ks[(mblk*32 + m32) * KS_PAD + ks*16 + h*8];
      short8 bk1 = *(const short8*)&Ks[(mblk*32 + m32) * KS_PAD + (ks+8)*16 + h*8];
      sa_ = __builtin_amdgcn_mfma_f32_32x32x16_bf16(qf[ks],   bk0, sa_, 0, 0, 0);
      sb_ = __builtin_amdgcn_mfma_f32_32x32x16_bf16(qf[ks+8], bk1, sb_, 0, 0, 0);
    }
    #pragma unroll
    for (int reg = 0; reg < 16; ++reg) {
      float e = __expf(sa_[reg] + sb_[reg]);
      lsum[reg] += e;
      int qr = qblk*32 + (reg & 3) + 8*(reg >> 2) + 4*h;
      Ps[qr * PS_PAD + mblk*32 + m32] = f2bf(e);
    }
    __syncthreads();
    #pragma unroll
    for (int ks2 = 0; ks2 < 4; ++ks2) {
      short8 pf[2];
      #pragma unroll
      for (int qt = 0; qt < 2; ++qt)
        pf[qt] = *(const short8*)&Ps[(qt*32 + m32) * PS_PAD + ks2*16 + h*8];
      #pragma unroll
      for (int qt = 0; qt < 2; ++qt)
        #pragma unroll
        for (int ct = 0; ct < 2; ++ct)
          oacc[qt][ct] = __builtin_amdgcn_mfma_f32_32x32x16_bf16(pf[qt], vreg[ks2][ct], oacc[qt][ct], 0, 0, 0);
    }
  }

  #pragma unroll
  for (int reg = 0; reg < 16; ++reg) {
    float v = lsum[reg];
    v += __shfl_xor(v, 1);  v += __shfl_xor(v, 2);
    v += __shfl_xor(v, 4);  v += __shfl_xor(v, 8);
    v += __shfl_xor(v, 16);
    lsum[reg] = v;
  }
  if (m32 == 0) {
    #pragma unroll
    for (int reg = 0; reg < 16; ++reg) {
      int qr = qblk*32 + (reg & 3) + 8*(reg >> 2) + 4*h;
      Ls[mblk][qr] = lsum[reg];
    }
  }
  __syncthreads();
  if (t < 64) {
    float l = Ls[0][t] + Ls[1][t];
    l_arr[half * 16384 + b * 4096 + n0 + t] = l;
    Lc[t] = 1.f / l;
  }
  __syncthreads();
  unsigned short* pB = (half ? P2 : P1) + (size_t)b * CHW;
  #pragma unroll
  for (int qt = 0; qt < 2; ++qt)
    #pragma unroll
    for (int reg = 0; reg < 16; ++reg) {
      int q = qt*32 + (reg & 3) + 8*(reg >> 2) + 4*h;
      float linv = Lc[q];
      #pragma unroll
      for (int ct = 0; ct < 2; ++ct)
        pB[(size_t)(n0 + q) * 256 + w*64 + ct*32 + m32] =
            f2bf(oacc[qt][ct][reg] * linv);
    }
}

// ---------------- proj GEMM + inline merge + bias + residual, 512 blocks ----
__global__ __launch_bounds__(256) void proj_kernel(const unsigned short* __restrict__ P1,
    const unsigned short* __restrict__ P2, const float* __restrict__ l_arr,
    const unsigned short* __restrict__ wpb, const float* __restrict__ bp,
    const float* __restrict__ x, float* __restrict__ out) {
  int ox = blockIdx.x, stile = blockIdx.y, b = blockIdx.z;   // grid (4,32,4)
  int t = threadIdx.x, w = t >> 6, lane = t & 63;
  int n16 = lane & 15, q8 = lane >> 4;
  int o0 = ox * 64;
  int sBase = stile * 128 + w * 32;
  const unsigned short* p1B = P1 + (size_t)b * CHW;
  const unsigned short* p2B = P2 + (size_t)b * CHW;

  float w1v[2], w2v[2];
  #pragma unroll
  for (int nt = 0; nt < 2; ++nt) {
    int s = sBase + nt*16 + n16;
    float l1 = l_arr[b*4096 + s], l2 = l_arr[16384 + b*4096 + s];
    float inv = 1.f / (l1 + l2);
    w1v[nt] = l1 * inv; w2v[nt] = l2 * inv;
  }
  float4 bias4[4];
  #pragma unroll
  for (int mt = 0; mt < 4; ++mt)
    bias4[mt] = *(const float4*)&bp[o0 + mt*16 + q8*4];

  floatx4 acc[4][2];
  #pragma unroll
  for (int i = 0; i < 4; ++i)
    #pragma unroll
    for (int j = 0; j < 2; ++j) acc[i][j] = (floatx4){0.f,0.f,0.f,0.f};

  for (int kt = 0; kt < 8; ++kt) {
    short8 af[4], bf[2];
    #pragma unroll
    for (int mt = 0; mt < 4; ++mt)
      af[mt] = *(const short8*)&wpb[(size_t)(o0 + mt*16 + n16) * 256 + kt*32 + q8*8];
    #pragma unroll
    for (int nt = 0; nt < 2; ++nt) {
      size_t off = (size_t)(sBase + nt*16 + n16) * 256 + kt*32 + q8*8;
      short8 a = *(const short8*)&p1B[off];
      short8 c = *(const short8*)&p2B[off];
      #pragma unroll
      for (int j = 0; j < 8; ++j)
        bf[nt][j] = (short)f2bf(w1v[nt] * bf2f((unsigned short)a[j]) +
                                w2v[nt] * bf2f((unsigned short)c[j]));
    }
    #pragma unroll
    for (int mt = 0; mt < 4; ++mt)
      #pragma unroll
      for (int nt = 0; nt < 2; ++nt)
        acc[mt][nt] = __builtin_amdgcn_mfma_f32_16x16x32_bf16(af[mt], bf[nt], acc[mt][nt], 0, 0, 0);
  }
  const float* xB = x + (size_t)b * CHW;
  float* oB = out + (size_t)b * CHW;
  #pragma unroll
  for (int mt = 0; mt < 4; ++mt)
    #pragma unroll
    for (int nt = 0; nt < 2; ++nt) {
      float bb[4] = {bias4[mt].x, bias4[mt].y, bias4[mt].z, bias4[mt].w};
      #pragma unroll
      for (int r = 0; r < 4; ++r) {
        size_t idx = (size_t)(o0 + mt*16 + q8*4 + r) * HW + sBase + nt*16 + n16;
        oB[idx] = xB[idx] + bb[r] + acc[mt][nt][r];
      }
    }
}

extern "C" void kernel_launch(void* const* d_in, const int* in_sizes, int n_in,
                              void* d_out, int out_size, void* d_ws, size_t ws_size,
                              hipStream_t stream) {
  const float* x  = (const float*)d_in[0];
  const float* gw = (const float*)d_in[1];
  const float* gb = (const float*)d_in[2];
  const float* wq = (const float*)d_in[3];
  const float* bq = (const float*)d_in[4];
  const float* wk = (const float*)d_in[5];
  const float* bk = (const float*)d_in[6];
  const float* wv = (const float*)d_in[7];
  const float* bv = (const float*)d_in[8];
  const float* wp = (const float*)d_in[9];
  const float* bp = (const float*)d_in[10];
  float* out = (float*)d_out;
  float* ws  = (float*)d_ws;

  // units of CHW floats (4 MiB each):
  unsigned short* hT    = (unsigned short*)ws;                      // 0-1
  unsigned short* qbp   = (unsigned short*)(ws + (size_t)2*CHW);    // 2-3
  unsigned short* kbp   = (unsigned short*)(ws + (size_t)4*CHW);    // 4-5
  unsigned short* vbp   = (unsigned short*)(ws + (size_t)6*CHW);    // 6-7 (packed)
  unsigned short* P1    = (unsigned short*)(ws + (size_t)8*CHW);    // 8-9
  unsigned short* P2    = (unsigned short*)(ws + (size_t)10*CHW);   // 10-11
  float*          l_arr = ws + (size_t)12*CHW;                      // 32768 floats
  unsigned short* wbuf  = (unsigned short*)(ws + (size_t)12*CHW + 65536); // 512 KB

  unsigned short* wqb = wbuf;
  unsigned short* wkb = wbuf + 65536;
  unsigned short* wvb = wbuf + 2*65536;
  unsigned short* wpb = wbuf + 3*65536;

  gn_kernel<<<dim3(288), dim3(256), 0, stream>>>(x, gw, gb, hT, wq, wk, wv, wp, wbuf);
  qkv_kernel<<<dim3(64, 3, 4), dim3(256), 0, stream>>>(hT, wqb, bq, wkb, bk, wvb, bv, qbp, kbp, vbp);
  att_kernel<<<dim3(64, 2, 4), dim3(256), 0, stream>>>(qbp, kbp, vbp, P1, P2, l_arr);
  proj_kernel<<<dim3(4, 32, 4), dim3(256), 0, stream>>>(P1, P2, l_arr, wpb, bp, x, out);
}

// Round 14
// 214.234 us; speedup vs baseline: 1.1887x; 1.1887x over previous
//
#include <hip/hip_runtime.h>

#define C 256
#define HW 4096
#define CHW (C*HW)            // 1048576 elements per batch per tensor (2^20)
#define CPG 8
#define GELEMS (CPG*HW)

typedef __attribute__((ext_vector_type(8))) short short8;     // 8 bf16 = 4 VGPRs
typedef __attribute__((ext_vector_type(4))) float floatx4;    // 16x16 C/D frag
typedef __attribute__((ext_vector_type(16))) float floatx16;  // 32x32 C/D frag

__device__ __forceinline__ unsigned short f2bf(float x) {
  union { float f; unsigned int u; } v; v.f = x;
  unsigned int r = v.u + 0x7FFF + ((v.u >> 16) & 1);   // RNE
  return (unsigned short)(r >> 16);
}
__device__ __forceinline__ float bf2f(unsigned short u) {
  union { float f; unsigned int v; } x; x.v = ((unsigned int)u) << 16; return x.f;
}

// ---------------- GroupNorm -> hT (b,s,c) bf16  +  weight cast ----------------
__global__ __launch_bounds__(256) void gn_kernel(const float* __restrict__ x,
    const float* __restrict__ gw, const float* __restrict__ gb,
    unsigned short* __restrict__ hT,
    const float* __restrict__ wq, const float* __restrict__ wk,
    const float* __restrict__ wv, const float* __restrict__ wp,
    unsigned short* __restrict__ wbuf) {
  int blk = blockIdx.x;
  int t = threadIdx.x;

  if (blk >= 256) {
    int r = blk - 256;
    int y = r >> 3, sub = r & 7;
    const float* src = (y == 0) ? wq : (y == 1) ? wk : (y == 2) ? wv : wp;
    int i = sub * 8192 + t * 4;
    float4 v = *(const float4*)(src + i);
    ushort4 u;
    u.x = f2bf(v.x); u.y = f2bf(v.y); u.z = f2bf(v.z); u.w = f2bf(v.w);
    *(ushort4*)(wbuf + y * 65536 + i) = u;
    return;
  }

  int gq = blk >> 1, halfg = blk & 1;   // group 0..127 (b*32+g), half 0/1
  int b = gq >> 5, g = gq & 31;
  const float* xg = x + (size_t)gq * GELEMS;
  const float4* x4 = (const float4*)xg;

  float s = 0.f, ss = 0.f;
  for (int i = t; i < GELEMS/4; i += 256) {
    float4 v = x4[i];
    s  += v.x + v.y + v.z + v.w;
    ss += v.x*v.x + v.y*v.y + v.z*v.z + v.w*v.w;
  }
  #pragma unroll
  for (int off = 32; off > 0; off >>= 1) {
    s  += __shfl_down(s,  off, 64);
    ss += __shfl_down(ss, off, 64);
  }
  __shared__ float rs[4], rss[4];
  __shared__ float smean, sinv;
  int wid = t >> 6;
  if ((t & 63) == 0) { rs[wid] = s; rss[wid] = ss; }
  __syncthreads();
  if (t == 0) {
    float S  = rs[0] + rs[1] + rs[2] + rs[3];
    float SS = rss[0] + rss[1] + rss[2] + rss[3];
    float mean = S / (float)GELEMS;
    float var  = SS / (float)GELEMS - mean * mean;
    smean = mean;
    sinv  = rsqrtf(var + 1e-5f);
  }
  __syncthreads();
  float mean = smean, inv = sinv;
  float sa[8], sb[8];
  #pragma unroll
  for (int cc = 0; cc < 8; ++cc) {
    sa[cc] = inv * gw[g*CPG + cc];
    sb[cc] = gb[g*CPG + cc] - mean * sa[cc];
  }
  int sbeg = halfg * 2048;
  #pragma unroll
  for (int p = 0; p < 8; ++p) {
    int sl = sbeg + p*256 + t;
    short8 pk;
    #pragma unroll
    for (int cc = 0; cc < 8; ++cc)
      pk[cc] = (short)f2bf(xg[cc*HW + sl] * sa[cc] + sb[cc]);
    *(short8*)&hT[((size_t)b*HW + sl) * 256 + g*CPG] = pk;
  }
}

// ---------------- fused QKV GEMM ----------
// q,k: fp8 e4m3 (s,c) layout, UNSCALED (C^-0.5 folded into att's exp).
// v: bf16 MFMA-B-fragment packed tiles (16s x 32c, 1 KB each).
__global__ __launch_bounds__(256) void qkv_kernel(const unsigned short* __restrict__ hT,
    const unsigned short* __restrict__ wqb, const float* __restrict__ bq,
    const unsigned short* __restrict__ wkb, const float* __restrict__ bk,
    const unsigned short* __restrict__ wvb, const float* __restrict__ bv,
    unsigned char* __restrict__ qo, unsigned char* __restrict__ ko,
    unsigned short* __restrict__ vo) {
  int stile = blockIdx.x, which = blockIdx.y, b = blockIdx.z;
  int t = threadIdx.x, w = t >> 6, lane = t & 63;
  int n16 = lane & 15, q8 = lane >> 4;
  int s0 = stile * 64;
  const unsigned short* hB = hT + (size_t)b * CHW;
  const unsigned short* W = (which == 0) ? wqb : (which == 1) ? wkb : wvb;
  const float* bias = (which == 0) ? bq : (which == 1) ? bk : bv;

  floatx4 acc[4][4];
  #pragma unroll
  for (int i = 0; i < 4; ++i)
    #pragma unroll
    for (int j = 0; j < 4; ++j) acc[i][j] = (floatx4){0.f,0.f,0.f,0.f};

  for (int kt = 0; kt < 8; ++kt) {
    short8 af[4], bf[4];
    #pragma unroll
    for (int mt = 0; mt < 4; ++mt)
      af[mt] = *(const short8*)&hB[(size_t)(s0 + mt*16 + n16) * 256 + kt*32 + q8*8];
    #pragma unroll
    for (int nt = 0; nt < 4; ++nt)
      bf[nt] = *(const short8*)&W[(size_t)(w*64 + nt*16 + n16) * 256 + kt*32 + q8*8];
    #pragma unroll
    for (int mt = 0; mt < 4; ++mt)
      #pragma unroll
      for (int nt = 0; nt < 4; ++nt)
        acc[mt][nt] = __builtin_amdgcn_mfma_f32_16x16x32_bf16(af[mt], bf[nt], acc[mt][nt], 0, 0, 0);
  }
  float bias_v[4];
  #pragma unroll
  for (int nt = 0; nt < 4; ++nt) bias_v[nt] = bias[w*64 + nt*16 + n16];

  if (which < 2) {
    // fp8 scatter stores (s,c); values unscaled
    unsigned char* oB = (which ? ko : qo) + (size_t)b * CHW;
    #pragma unroll
    for (int mt = 0; mt < 4; ++mt)
      #pragma unroll
      for (int nt = 0; nt < 4; ++nt) {
        float v0 = acc[mt][nt][0] + bias_v[nt];
        float v1 = acc[mt][nt][1] + bias_v[nt];
        float v2 = acc[mt][nt][2] + bias_v[nt];
        float v3 = acc[mt][nt][3] + bias_v[nt];
        unsigned int p01 = __builtin_amdgcn_cvt_pk_fp8_f32(v0, v1, 0, false);
        unsigned int p23 = __builtin_amdgcn_cvt_pk_fp8_f32(v2, v3, 0, false);
        int col = w*64 + nt*16 + n16;
        size_t r0 = (size_t)(s0 + mt*16 + q8*4) * 256 + col;
        oB[r0 +   0] = (unsigned char)(p01 & 0xFF);
        oB[r0 + 256] = (unsigned char)((p01 >> 8) & 0xFF);
        oB[r0 + 512] = (unsigned char)(p23 & 0xFF);
        oB[r0 + 768] = (unsigned char)((p23 >> 8) & 0xFF);
      }
  } else {
    // packed bf16 V store
    unsigned short* vB = vo + (size_t)b * CHW;
    #pragma unroll
    for (int mt = 0; mt < 4; ++mt) {
      int st = stile*4 + mt;
      #pragma unroll
      for (int nt = 0; nt < 4; ++nt) {
        int c = w*64 + nt*16 + n16;
        int ct8 = c >> 5, c5 = c & 31;
        #pragma unroll
        for (int r = 0; r < 4; ++r) {
          int sl = q8*4 + r;
          int hh = sl >> 3, e = sl & 7;
          vB[((size_t)st*8 + ct8)*512 + (hh*32 + c5)*8 + e] =
              f2bf(acc[mt][nt][r] + bias_v[nt]);
        }
      }
    }
  }
}

// ---------------- MFMA flash attention: fp8 QK, bf16 PV, split-K halves ----
// qb,kb (b,s,c) fp8; vb packed bf16 B-frag tiles. Grid (64,2,4) = 512 = 2/CU.
#define KS8_PAD 264  // BYTES per Ks row (256 + 8): b64 reads 2-way (free)
#define PS_PAD 72    // shorts per Ps row (64 + 8)

__global__ __launch_bounds__(256, 2) void att_kernel(
    const unsigned char* __restrict__ qb,
    const unsigned char* __restrict__ kb,
    const unsigned short* __restrict__ vb,
    unsigned short* __restrict__ P1, unsigned short* __restrict__ P2,
    float* __restrict__ l_arr) {
  __shared__ __align__(16) unsigned char Ks8[64 * KS8_PAD];   // 16.9 KB
  __shared__ __align__(16) unsigned short Ps[64 * PS_PAD];
  __shared__ float Ls[2][64];
  __shared__ float Lc[64];

  int t = threadIdx.x, w = t >> 6, lane = t & 63;
  int m32 = lane & 31;
  int h   = lane >> 5;
  int qblk = w & 1;
  int mblk = w >> 1;
  int n0 = blockIdx.x * 64, half = blockIdx.y, b = blockIdx.z;

  const unsigned char* qB = qb + (size_t)b * CHW;
  const unsigned char* kB = kb + (size_t)b * CHW;
  const unsigned short* vB = vb + (size_t)b * CHW;

  // Q fragments (fp8 A operand, 32x32x16): lane row n0+qblk*32+m32, k bytes h*8+e
  long qf8[16];
  {
    const unsigned char* qp = qB + (size_t)(n0 + qblk*32 + m32) * 256 + h*8;
    #pragma unroll
    for (int ks = 0; ks < 16; ++ks) qf8[ks] = *(const long*)(qp + ks*16);
  }

  float lsum[16];
  #pragma unroll
  for (int r = 0; r < 16; ++r) lsum[r] = 0.f;
  floatx16 oacc[2][2];   // [qt][ct]
  #pragma unroll
  for (int i = 0; i < 2; ++i)
    #pragma unroll
    for (int j = 0; j < 2; ++j)
      #pragma unroll
      for (int r = 0; r < 16; ++r) oacc[i][j][r] = 0.f;

  // staging: K chunk = 64 rows x 256 B; thread t covers row t>>2, 64 B at (t&3)*64
  int krow = t >> 2, kcb = (t & 3) * 64;
  int mc_beg = half * 32, mc_end = mc_beg + 32;
  uint4 kreg[4];
  #pragma unroll
  for (int i = 0; i < 4; ++i)
    kreg[i] = *(const uint4*)(kB + (size_t)(mc_beg*64 + krow) * 256 + kcb + i*16);

  for (int mc = mc_beg; mc < mc_end; ++mc) {
    int m0 = mc * 64;
    // stage current K chunk (b64 writes, pitch 264 B)
    #pragma unroll
    for (int i = 0; i < 4; ++i) {
      *(uint2*)&Ks8[krow * KS8_PAD + kcb + i*16]     = make_uint2(kreg[i].x, kreg[i].y);
      *(uint2*)&Ks8[krow * KS8_PAD + kcb + i*16 + 8] = make_uint2(kreg[i].z, kreg[i].w);
    }
    __syncthreads();
    // prefetch next K chunk
    if (mc + 1 < mc_end) {
      #pragma unroll
      for (int i = 0; i < 4; ++i)
        kreg[i] = *(const uint4*)(kB + (size_t)(m0 + 64 + krow) * 256 + kcb + i*16);
    }
    // V B-fragments: packed bf16 tiles, 1 coalesced b128 each
    short8 vreg[4][2];
    #pragma unroll
    for (int ks2 = 0; ks2 < 4; ++ks2)
      #pragma unroll
      for (int ct = 0; ct < 2; ++ct)
        vreg[ks2][ct] = *(const short8*)(vB +
            ((size_t)(mc*4 + ks2)*8 + (w*2 + ct))*512 + lane*8);

    // ---- S = Q·K^T (fp8): 2 independent 8-step chains ----
    floatx16 sa_, sb_;
    #pragma unroll
    for (int r = 0; r < 16; ++r) { sa_[r] = 0.f; sb_[r] = 0.f; }
    #pragma unroll
    for (int ks = 0; ks < 8; ++ks) {
      long bk0 = *(const long*)&Ks8[(mblk*32 + m32) * KS8_PAD + ks*16 + h*8];
      long bk1 = *(const long*)&Ks8[(mblk*32 + m32) * KS8_PAD + (ks+8)*16 + h*8];
      sa_ = __builtin_amdgcn_mfma_f32_32x32x16_fp8_fp8(qf8[ks],   bk0, sa_, 0, 0, 0);
      sb_ = __builtin_amdgcn_mfma_f32_32x32x16_fp8_fp8(qf8[ks+8], bk1, sb_, 0, 0, 0);
    }
    // ---- no-max softmax with C^-0.5 folded into exp; row reduction deferred ----
    #pragma unroll
    for (int reg = 0; reg < 16; ++reg) {
      float e = __expf((sa_[reg] + sb_[reg]) * 0.0625f);
      lsum[reg] += e;
      int qr = qblk*32 + (reg & 3) + 8*(reg >> 2) + 4*h;
      Ps[qr * PS_PAD + mblk*32 + m32] = f2bf(e);
    }
    __syncthreads();
    // ---- O += P·V (bf16) ----
    #pragma unroll
    for (int ks2 = 0; ks2 < 4; ++ks2) {
      short8 pf[2];
      #pragma unroll
      for (int qt = 0; qt < 2; ++qt)
        pf[qt] = *(const short8*)&Ps[(qt*32 + m32) * PS_PAD + ks2*16 + h*8];
      #pragma unroll
      for (int qt = 0; qt < 2; ++qt)
        #pragma unroll
        for (int ct = 0; ct < 2; ++ct)
          oacc[qt][ct] = __builtin_amdgcn_mfma_f32_32x32x16_bf16(pf[qt], vreg[ks2][ct], oacc[qt][ct], 0, 0, 0);
    }
  }

  // ---- epilogue: reduce l, normalize, write partial (n,c) + l ----
  #pragma unroll
  for (int reg = 0; reg < 16; ++reg) {
    float v = lsum[reg];
    v += __shfl_xor(v, 1);  v += __shfl_xor(v, 2);
    v += __shfl_xor(v, 4);  v += __shfl_xor(v, 8);
    v += __shfl_xor(v, 16);
    lsum[reg] = v;
  }
  if (m32 == 0) {
    #pragma unroll
    for (int reg = 0; reg < 16; ++reg) {
      int qr = qblk*32 + (reg & 3) + 8*(reg >> 2) + 4*h;
      Ls[mblk][qr] = lsum[reg];
    }
  }
  __syncthreads();
  if (t < 64) {
    float l = Ls[0][t] + Ls[1][t];
    l_arr[half * 16384 + b * 4096 + n0 + t] = l;
    Lc[t] = 1.f / l;
  }
  __syncthreads();
  unsigned short* pB = (half ? P2 : P1) + (size_t)b * CHW;
  #pragma unroll
  for (int qt = 0; qt < 2; ++qt)
    #pragma unroll
    for (int reg = 0; reg < 16; ++reg) {
      int q = qt*32 + (reg & 3) + 8*(reg >> 2) + 4*h;
      float linv = Lc[q];
      #pragma unroll
      for (int ct = 0; ct < 2; ++ct)
        pB[(size_t)(n0 + q) * 256 + w*64 + ct*32 + m32] =
            f2bf(oacc[qt][ct][reg] * linv);
    }
}

// ---------------- proj GEMM + inline merge + bias + residual, 512 blocks ----
__global__ __launch_bounds__(256) void proj_kernel(const unsigned short* __restrict__ P1,
    const unsigned short* __restrict__ P2, const float* __restrict__ l_arr,
    const unsigned short* __restrict__ wpb, const float* __restrict__ bp,
    const float* __restrict__ x, float* __restrict__ out) {
  int ox = blockIdx.x, stile = blockIdx.y, b = blockIdx.z;   // grid (4,32,4)
  int t = threadIdx.x, w = t >> 6, lane = t & 63;
  int n16 = lane & 15, q8 = lane >> 4;
  int o0 = ox * 64;
  int sBase = stile * 128 + w * 32;
  const unsigned short* p1B = P1 + (size_t)b * CHW;
  const unsigned short* p2B = P2 + (size_t)b * CHW;

  float w1v[2], w2v[2];
  #pragma unroll
  for (int nt = 0; nt < 2; ++nt) {
    int s = sBase + nt*16 + n16;
    float l1 = l_arr[b*4096 + s], l2 = l_arr[16384 + b*4096 + s];
    float inv = 1.f / (l1 + l2);
    w1v[nt] = l1 * inv; w2v[nt] = l2 * inv;
  }
  float4 bias4[4];
  #pragma unroll
  for (int mt = 0; mt < 4; ++mt)
    bias4[mt] = *(const float4*)&bp[o0 + mt*16 + q8*4];

  floatx4 acc[4][2];
  #pragma unroll
  for (int i = 0; i < 4; ++i)
    #pragma unroll
    for (int j = 0; j < 2; ++j) acc[i][j] = (floatx4){0.f,0.f,0.f,0.f};

  for (int kt = 0; kt < 8; ++kt) {
    short8 af[4], bf[2];
    #pragma unroll
    for (int mt = 0; mt < 4; ++mt)
      af[mt] = *(const short8*)&wpb[(size_t)(o0 + mt*16 + n16) * 256 + kt*32 + q8*8];
    #pragma unroll
    for (int nt = 0; nt < 2; ++nt) {
      size_t off = (size_t)(sBase + nt*16 + n16) * 256 + kt*32 + q8*8;
      short8 a = *(const short8*)&p1B[off];
      short8 c = *(const short8*)&p2B[off];
      #pragma unroll
      for (int j = 0; j < 8; ++j)
        bf[nt][j] = (short)f2bf(w1v[nt] * bf2f((unsigned short)a[j]) +
                                w2v[nt] * bf2f((unsigned short)c[j]));
    }
    #pragma unroll
    for (int mt = 0; mt < 4; ++mt)
      #pragma unroll
      for (int nt = 0; nt < 2; ++nt)
        acc[mt][nt] = __builtin_amdgcn_mfma_f32_16x16x32_bf16(af[mt], bf[nt], acc[mt][nt], 0, 0, 0);
  }
  const float* xB = x + (size_t)b * CHW;
  float* oB = out + (size_t)b * CHW;
  #pragma unroll
  for (int mt = 0; mt < 4; ++mt)
    #pragma unroll
    for (int nt = 0; nt < 2; ++nt) {
      float bb[4] = {bias4[mt].x, bias4[mt].y, bias4[mt].z, bias4[mt].w};
      #pragma unroll
      for (int r = 0; r < 4; ++r) {
        size_t idx = (size_t)(o0 + mt*16 + q8*4 + r) * HW + sBase + nt*16 + n16;
        oB[idx] = xB[idx] + bb[r] + acc[mt][nt][r];
      }
    }
}

extern "C" void kernel_launch(void* const* d_in, const int* in_sizes, int n_in,
                              void* d_out, int out_size, void* d_ws, size_t ws_size,
                              hipStream_t stream) {
  const float* x  = (const float*)d_in[0];
  const float* gw = (const float*)d_in[1];
  const float* gb = (const float*)d_in[2];
  const float* wq = (const float*)d_in[3];
  const float* bq = (const float*)d_in[4];
  const float* wk = (const float*)d_in[5];
  const float* bk = (const float*)d_in[6];
  const float* wv = (const float*)d_in[7];
  const float* bv = (const float*)d_in[8];
  const float* wp = (const float*)d_in[9];
  const float* bp = (const float*)d_in[10];
  float* out = (float*)d_out;
  float* ws  = (float*)d_ws;

  // units of CHW floats (4 MiB each):
  unsigned short* hT    = (unsigned short*)ws;                      // 0-1
  unsigned char*  qbp   = (unsigned char*)(ws + (size_t)2*CHW);     // 2 (fp8, 4 MB)
  unsigned char*  kbp   = (unsigned char*)(ws + (size_t)4*CHW);     // 4 (fp8, 4 MB)
  unsigned short* vbp   = (unsigned short*)(ws + (size_t)6*CHW);    // 6-7 (packed bf16)
  unsigned short* P1    = (unsigned short*)(ws + (size_t)8*CHW);    // 8-9
  unsigned short* P2    = (unsigned short*)(ws + (size_t)10*CHW);   // 10-11
  float*          l_arr = ws + (size_t)12*CHW;                      // 32768 floats
  unsigned short* wbuf  = (unsigned short*)(ws + (size_t)12*CHW + 65536); // 512 KB

  unsigned short* wqb = wbuf;
  unsigned short* wkb = wbuf + 65536;
  unsigned short* wvb = wbuf + 2*65536;
  unsigned short* wpb = wbuf + 3*65536;

  gn_kernel<<<dim3(288), dim3(256), 0, stream>>>(x, gw, gb, hT, wq, wk, wv, wp, wbuf);
  qkv_kernel<<<dim3(64, 3, 4), dim3(256), 0, stream>>>(hT, wqb, bq, wkb, bk, wvb, bv, qbp, kbp, vbp);
  att_kernel<<<dim3(64, 2, 4), dim3(256), 0, stream>>>(qbp, kbp, vbp, P1, P2, l_arr);
  proj_kernel<<<dim3(4, 32, 4), dim3(256), 0, stream>>>(P1, P2, l_arr, wpb, bp, x, out);
}